// Round 7
// baseline (353.806 us; speedup 1.0000x reference)
//
#include <hip/hip_runtime.h>
#include <hip/hip_bf16.h>

// ---------------------------------------------------------------------------
// TransformerBlock: LN1 -> QKV -> leaky-relu attention -> Wo+res -> LN2 ->
//                   FFN1(leaky) -> FFN2+res
// B=2 N=2048 EMB=1024 H=16 HD=64 FFN=4096.
// Round 7: gemm_core128 + attn_k both use a 3-deep LDS ring with counted
// vmcnt(4) + raw s_barrier (never drain to 0 mid-loop): tile t+2 staged
// behind the barrier, 2 tiles in flight. 48 KB LDS -> 3 blocks/CU.
// ---------------------------------------------------------------------------

typedef unsigned short u16;
typedef unsigned int u32;
typedef __bf16 bf16x8 __attribute__((ext_vector_type(8)));
typedef __bf16 bf16x4 __attribute__((ext_vector_type(4)));
typedef float f32x4 __attribute__((ext_vector_type(4)));
typedef unsigned short u16x8 __attribute__((ext_vector_type(8)));
typedef unsigned int u32x2 __attribute__((ext_vector_type(2)));
typedef short s16x4 __attribute__((ext_vector_type(4)));

typedef const __attribute__((address_space(1))) void* as1cv;
typedef __attribute__((address_space(3))) void* as3v;

#define MFMA16(a, b, c) __builtin_amdgcn_mfma_f32_16x16x32_bf16((a), (b), (c), 0, 0, 0)
#define GLL16(g, l) __builtin_amdgcn_global_load_lds((as1cv)(g), (as3v)(l), 16, 0, 0)

__device__ __forceinline__ u16 f2bf(float f) {
  unsigned u = __builtin_bit_cast(unsigned, f);
  u += 0x7fffu + ((u >> 16) & 1u);   // RNE
  return (u16)(u >> 16);
}
__device__ __forceinline__ float bf2f(u16 u) {
  return __builtin_bit_cast(float, ((unsigned)u) << 16);
}
__device__ __forceinline__ float lrelu(float v) { return fmaxf(v, 0.01f * v); }

// PV matrix op: D[16d x 16q] += A[16d x 16k] * B[16k x 16q], bf16 inputs.
__device__ __forceinline__ void mfma16x16(f32x4& c, bf16x4 a, bf16x4 b) {
#if __has_builtin(__builtin_amdgcn_mfma_f32_16x16x16bf16_1k)
  c = __builtin_amdgcn_mfma_f32_16x16x16bf16_1k(
      __builtin_bit_cast(s16x4, a), __builtin_bit_cast(s16x4, b), c, 0, 0, 0);
#else
  u32x2 au = __builtin_bit_cast(u32x2, a);
  u32x2 bu = __builtin_bit_cast(u32x2, b);
  asm volatile("s_nop 2\n\tv_mfma_f32_16x16x16_bf16 %0, %1, %2, %0"
               : "+v"(c) : "v"(au), "v"(bu));
#endif
}

// XCD-aware bijective swizzle (nwg % 8 == 0): XCD x gets contiguous chunk.
__device__ __forceinline__ int xcds(int bid, int nwg) {
  int cpx = nwg >> 3;
  return (bid & 7) * cpx + (bid >> 3);
}

// ------------------- weight f32 -> bf16 ------------------------------------
__global__ __launch_bounds__(256) void cvt6(
    const float* __restrict__ p0, const float* __restrict__ p1,
    const float* __restrict__ p2, const float* __restrict__ p3,
    const float* __restrict__ p4, const float* __restrict__ p5,
    u16* __restrict__ o0, u16* __restrict__ o1, u16* __restrict__ o2,
    u16* __restrict__ o3, u16* __restrict__ o4, u16* __restrict__ o5)
{
  int i = blockIdx.x * 256 + threadIdx.x;   // unit = 8 elements
  const float* src; u16* dst; int off;
  if (i < 4 * 131072) {
    int s = i >> 17; off = i & 131071;
    src = (s == 0) ? p0 : (s == 1) ? p1 : (s == 2) ? p2 : p3;
    dst = (s == 0) ? o0 : (s == 1) ? o1 : (s == 2) ? o2 : o3;
  } else {
    int j = i - 4 * 131072;
    int s = j >> 19; off = j & 524287;
    src = s ? p5 : p4;
    dst = s ? o5 : o4;
  }
  const float4* s4 = (const float4*)src;
  float4 a = s4[(size_t)off * 2], b = s4[(size_t)off * 2 + 1];
  u16x8 o = { f2bf(a.x), f2bf(a.y), f2bf(a.z), f2bf(a.w),
              f2bf(b.x), f2bf(b.y), f2bf(b.z), f2bf(b.w) };
  *(u16x8*)(dst + (size_t)off * 8) = o;
}

// ------------------- LayerNorm row (1024) f32 -> bf16 ----------------------
__global__ __launch_bounds__(256) void ln_k(
    const float* __restrict__ x, const float* __restrict__ g,
    const float* __restrict__ bb, u16* __restrict__ out)
{
  const int tid = threadIdx.x;
  const int row = blockIdx.x;
  const float4* xr = (const float4*)(x + (size_t)row * 1024);
  float4 v = xr[tid];
  float s  = v.x + v.y + v.z + v.w;
  float s2 = v.x*v.x + v.y*v.y + v.z*v.z + v.w*v.w;
#pragma unroll
  for (int o = 32; o > 0; o >>= 1) { s += __shfl_down(s, o, 64); s2 += __shfl_down(s2, o, 64); }
  __shared__ float sh[8];
  if ((tid & 63) == 0) { sh[tid >> 6] = s; sh[4 + (tid >> 6)] = s2; }
  __syncthreads();
  s  = sh[0] + sh[1] + sh[2] + sh[3];
  s2 = sh[4] + sh[5] + sh[6] + sh[7];
  float mu  = s * (1.0f / 1024.0f);
  float var = s2 * (1.0f / 1024.0f) - mu * mu;
  float rs  = rsqrtf(var + 1e-6f);
  float4 gv = ((const float4*)g)[tid];
  float4 bv = ((const float4*)bb)[tid];
  ushort4 o;
  o.x = f2bf((v.x - mu) * rs * gv.x + bv.x);
  o.y = f2bf((v.y - mu) * rs * gv.y + bv.y);
  o.z = f2bf((v.z - mu) * rs * gv.z + bv.z);
  o.w = f2bf((v.w - mu) * rs * gv.w + bv.w);
  ((ushort4*)out)[(size_t)row * 256 + tid] = o;
}

// ------------------- GEMM core: C[128,128] tile, A[M,K] x W[N,K]^T ---------
// 256 threads = 4 waves (2x2 of 64x64). BK=32. 3-deep LDS ring, counted
// vmcnt(4) + raw s_barrier: tile t+2 staged behind the barrier, 2 tiles in
// flight, never drained to 0 mid-loop. Buffer-reuse distance = 1 barrier
// (reads of buf b complete into regs before the barrier; overwrite issues
// after it).
__device__ __forceinline__ void gemm_core128(
    const u16* __restrict__ A, const u16* __restrict__ W,
    int kstride, int klen,
    int row0, int wrow0, u16* lsA, u16* lsB, f32x4 (&acc)[4][4])
{
  const int tid  = threadIdx.x;
  const int lane = tid & 63, wave = tid >> 6;
  const int wr = wave >> 1, wc = wave & 1;
  const int lr = lane & 15, lg = lane >> 4;

  const u16* ga0 = A + (size_t)(row0 + (tid >> 2)) * kstride + (tid & 3) * 8;
  const u16* ga1 = ga0 + (size_t)64 * kstride;
  const u16* gb0 = W + (size_t)(wrow0 + (tid >> 2)) * kstride + (tid & 3) * 8;
  const u16* gb1 = gb0 + (size_t)64 * kstride;
  u16* la = lsA + tid * 8;            // linear, wave-contiguous (GLL dest rule)
  u16* lb = lsB + tid * 8;

#define GSTAGE(buf)                                                  \
  {                                                                  \
    GLL16(ga0, la + (buf) * 4096);                                   \
    GLL16(ga1, la + (buf) * 4096 + 2048);                            \
    GLL16(gb0, lb + (buf) * 4096);                                   \
    GLL16(gb1, lb + (buf) * 4096 + 2048);                            \
    ga0 += 32; ga1 += 32; gb0 += 32; gb1 += 32;                      \
  }

  const int nsteps = klen >> 5;
  GSTAGE(0); GSTAGE(1);               // prologue: tiles 0,1 in flight

  int bi = 0;                         // buffer holding tile t
  int bs = 2;                         // buffer for tile t+2
  for (int t = 0; t < nsteps; t++) {
    // my tile-t loads done; tile t+1 stays in flight.
    if (t + 1 < nsteps) asm volatile("s_waitcnt vmcnt(4)" ::: "memory");
    else                asm volatile("s_waitcnt vmcnt(0)" ::: "memory");
    __builtin_amdgcn_s_barrier();
    asm volatile("" ::: "memory");
    if (t + 2 < nsteps) { GSTAGE(bs); bs = (bs == 2) ? 0 : bs + 1; }

    const u16* cA = lsA + bi * 4096;
    const u16* cB = lsB + bi * 4096;
    bf16x8 av[4], bv[4];
#pragma unroll
    for (int mi = 0; mi < 4; mi++)
      av[mi] = *reinterpret_cast<const bf16x8*>(cA + (wr * 64 + mi * 16 + lr) * 32 + lg * 8);
#pragma unroll
    for (int ni = 0; ni < 4; ni++)
      bv[ni] = *reinterpret_cast<const bf16x8*>(cB + (wc * 64 + ni * 16 + lr) * 32 + lg * 8);
#pragma unroll
    for (int mi = 0; mi < 4; mi++)
#pragma unroll
      for (int ni = 0; ni < 4; ni++)
        acc[mi][ni] = MFMA16(av[mi], bv[ni], acc[mi][ni]);
    bi = (bi == 2) ? 0 : bi + 1;
  }
#undef GSTAGE
}

// ------------------- fused QKV GEMM: N=3072, scatter epilogue --------------
// q stored pre-scaled by 1/8 (folds the 1/sqrt(HD) of the attention scores).
__global__ __launch_bounds__(256, 3) void gemm_qkv(
    const u16* __restrict__ xn,
    const u16* __restrict__ Wq, const u16* __restrict__ Wk, const u16* __restrict__ Wv,
    const float* __restrict__ bq, const float* __restrict__ bk, const float* __restrict__ bv,
    u16* __restrict__ qb, u16* __restrict__ kb, u16* __restrict__ vtb)
{
  __shared__ u16 lsA[3 * 4096];   // 24 KB
  __shared__ u16 lsB[3 * 4096];   // 24 KB
  const int wid = xcds(blockIdx.x, 768);
  const int mt = wid / 24, nt = wid % 24;
  const int row0 = mt * 128, col0 = nt * 128;
  const int sel = col0 >> 10, c0 = col0 & 1023;
  const u16* W = (sel == 0) ? Wq : (sel == 1) ? Wk : Wv;
  const float* bias = (sel == 0) ? bq : (sel == 1) ? bk : bv;

  f32x4 acc[4][4];
  f32x4 z = {0.f, 0.f, 0.f, 0.f};
#pragma unroll
  for (int mi = 0; mi < 4; mi++)
#pragma unroll
    for (int ni = 0; ni < 4; ni++) acc[mi][ni] = z;

  gemm_core128(xn, W, 1024, 1024, row0, c0, lsA, lsB, acc);

  const int lane = threadIdx.x & 63, wave = threadIdx.x >> 6;
  const int wr = wave >> 1, wc = wave & 1;
  const int lr = lane & 15, lg = lane >> 4;
  const float qscale = (sel == 0) ? 0.125f : 1.0f;
#pragma unroll
  for (int ni = 0; ni < 4; ni++) {
    int c = c0 + wc * 64 + ni * 16 + lr;        // 0..1023 within selected proj
    float bsv = bias[c];
    int h = c >> 6, hd = c & 63;
#pragma unroll
    for (int mi = 0; mi < 4; mi++) {
      int rbase = row0 + wr * 64 + mi * 16 + lg * 4;   // global row (4-aligned)
      int b = rbase >> 11;
      int n = rbase & 2047;
      if (sel < 2) {                 // q,k -> [B,H,N,HD]
        u16* dst = (sel == 0) ? qb : kb;
        size_t base = ((size_t)(b * 16 + h) * 2048 + n) * 64 + hd;
#pragma unroll
        for (int r = 0; r < 4; r++)
          dst[base + (size_t)r * 64] = f2bf((acc[mi][ni][r] + bsv) * qscale);
      } else {                       // v -> transposed [B,H,HD,N]
        size_t base = ((size_t)((b * 16 + h) * 64 + hd)) * 2048 + n;
        ushort4 o;
        o.x = f2bf(acc[mi][ni][0] + bsv);
        o.y = f2bf(acc[mi][ni][1] + bsv);
        o.z = f2bf(acc[mi][ni][2] + bsv);
        o.w = f2bf(acc[mi][ni][3] + bsv);
        *(ushort4*)(vtb + base) = o;
      }
    }
  }
}

// ------------------- generic GEMM + epilogue -------------------------------
// EPI 0: outf[idx] = acc + bias + extra[idx]           (f32; Wo+res)
// EPI 1: outh[idx] = bf16(lrelu(acc + bias))           (FFN1)
template <int EPI>
__global__ __launch_bounds__(256, 3) void gemm128(
    const u16* __restrict__ A, const u16* __restrict__ W,
    const float* __restrict__ bias, float* __restrict__ outf,
    u16* __restrict__ outh, const float* __restrict__ extra,
    int K, int nTiles, int nwg)
{
  __shared__ u16 lsA[3 * 4096];
  __shared__ u16 lsB[3 * 4096];
  const int wid = xcds(blockIdx.x, nwg);
  const int mt = wid / nTiles, nt = wid % nTiles;
  const int row0 = mt * 128, col0 = nt * 128;

  f32x4 acc[4][4];
  f32x4 z = {0.f, 0.f, 0.f, 0.f};
#pragma unroll
  for (int mi = 0; mi < 4; mi++)
#pragma unroll
    for (int ni = 0; ni < 4; ni++) acc[mi][ni] = z;

  gemm_core128(A, W, K, K, row0, col0, lsA, lsB, acc);

  const int N = nTiles * 128;
  const int lane = threadIdx.x & 63, wave = threadIdx.x >> 6;
  const int wr = wave >> 1, wc = wave & 1;
  const int lr = lane & 15, lg = lane >> 4;
#pragma unroll
  for (int ni = 0; ni < 4; ni++) {
    int col = col0 + wc * 64 + ni * 16 + lr;
    float bsv = bias[col];
#pragma unroll
    for (int mi = 0; mi < 4; mi++) {
      int rbase = row0 + wr * 64 + mi * 16 + lg * 4;
#pragma unroll
      for (int r = 0; r < 4; r++) {
        float v = acc[mi][ni][r] + bsv;
        size_t idx = (size_t)(rbase + r) * N + col;
        if (EPI == 0) {
          outf[idx] = v + extra[idx];
        } else {
          outh[idx] = f2bf(lrelu(v));
        }
      }
    }
  }
}

// ------------------- FFN2 split-K GEMM: 4 chunks of K=1024 -----------------
__global__ __launch_bounds__(256, 3) void gemm_ffn2(
    const u16* __restrict__ A, const u16* __restrict__ W,
    u16* __restrict__ pout)
{
  __shared__ u16 lsA[3 * 4096];
  __shared__ u16 lsB[3 * 4096];
  const int wid = xcds(blockIdx.x, 1024);
  const int chunk = wid >> 8, rem = wid & 255;
  const int mt = rem >> 3, nt = rem & 7;
  const int row0 = mt * 128, col0 = nt * 128;

  f32x4 acc[4][4];
  f32x4 z = {0.f, 0.f, 0.f, 0.f};
#pragma unroll
  for (int mi = 0; mi < 4; mi++)
#pragma unroll
    for (int ni = 0; ni < 4; ni++) acc[mi][ni] = z;

  gemm_core128(A + chunk * 1024, W + chunk * 1024, 4096, 1024,
               row0, col0, lsA, lsB, acc);

  u16* out = pout + (size_t)chunk * (4096 * 1024);
  const int lane = threadIdx.x & 63, wave = threadIdx.x >> 6;
  const int wr = wave >> 1, wc = wave & 1;
  const int lr = lane & 15, lg = lane >> 4;
#pragma unroll
  for (int ni = 0; ni < 4; ni++) {
    int col = col0 + wc * 64 + ni * 16 + lr;
#pragma unroll
    for (int mi = 0; mi < 4; mi++) {
      int rbase = row0 + wr * 64 + mi * 16 + lg * 4;
#pragma unroll
      for (int r = 0; r < 4; r++)
        out[(size_t)(rbase + r) * 1024 + col] = f2bf(acc[mi][ni][r]);
    }
  }
}

// ------------------- FFN2 reduce: out = sum(4 partials) + b2 + x2 ----------
__global__ __launch_bounds__(256) void reduce_ffn2(
    const u16* __restrict__ p, const float* __restrict__ b2,
    const float* __restrict__ x2, float* __restrict__ out)
{
  size_t i = ((size_t)blockIdx.x * 256 + threadIdx.x) * 4;
  int col = (int)(i & 1023);
  ushort4 a0 = *(const ushort4*)(p + i);
  ushort4 a1 = *(const ushort4*)(p + (size_t)(4096 * 1024) + i);
  ushort4 a2 = *(const ushort4*)(p + (size_t)(2 * 4096 * 1024) + i);
  ushort4 a3 = *(const ushort4*)(p + (size_t)(3 * 4096 * 1024) + i);
  float4 bv = *(const float4*)(b2 + col);
  float4 xv = *(const float4*)(x2 + i);
  float4 r;
  r.x = bf2f(a0.x) + bf2f(a1.x) + bf2f(a2.x) + bf2f(a3.x) + bv.x + xv.x;
  r.y = bf2f(a0.y) + bf2f(a1.y) + bf2f(a2.y) + bf2f(a3.y) + bv.y + xv.y;
  r.z = bf2f(a0.z) + bf2f(a1.z) + bf2f(a2.z) + bf2f(a3.z) + bv.z + xv.z;
  r.w = bf2f(a0.w) + bf2f(a1.w) + bf2f(a2.w) + bf2f(a3.w) + bv.w + xv.w;
  *(float4*)(out + i) = r;
}

// ------------------- attention v2: P in registers, ring-3 ------------------
// grid = 512 = (B*H=32) x (N/128=16). Block: 4 waves, each owns 32 q-rows.
// S'[k][q] = mfma_16x16x32(A=K, B=Q)  -> lane: q=lr, k=lg*4+r
// P' = lrelu(S')  (q pre-scaled 1/8)  == B-frag of mfma_16x16x16 exactly
// ctx'[d][q] += mfma_16x16x16(A=Vt, B=P')
// K/V: pre-swizzled global_load_lds, 3-buf ring (48 KB -> 3 blocks/CU),
// counted vmcnt(4) + raw s_barrier, stage t+2 behind the barrier.
__global__ __launch_bounds__(256, 3) void attn_k(
    const u16* __restrict__ qb, const u16* __restrict__ kb,
    const u16* __restrict__ vtb, u16* __restrict__ ctx)
{
  __shared__ u16 lds[3 * 8192];   // 3 bufs x (K[64][64] + Vt[64][64]) = 48 KB

  const int tid = threadIdx.x;
  const int lane = tid & 63, wq = tid >> 6;
  const int lr = lane & 15, lg = lane >> 4;
  const int wid = xcds(blockIdx.x, 512);
  const int bh = wid >> 4, qt = wid & 15;
  const int n0 = qt * 128;
  const u16* qh = qb + (size_t)bh * 2048 * 64;
  const u16* kh = kb + (size_t)bh * 2048 * 64;
  const u16* vh = vtb + (size_t)bh * 64 * 2048;

  // staging: thread covers LDS 16B-granules tid and tid+256 of each half.
  // LDS[row][gc] holds global granule gc^(row&7)  (swizzle via source).
  const int srow = tid >> 3;
  const int sgg  = (tid & 7) ^ (srow & 7);
  const size_t koff0 = (size_t)srow * 64 + sgg * 8;
  const size_t koff1 = koff0 + (size_t)32 * 64;
  const size_t voff0 = (size_t)srow * 2048 + sgg * 8;
  const size_t voff1 = voff0 + (size_t)32 * 2048;
  const int dk0 = tid * 8, dk1 = tid * 8 + 2048;  // u16 units inside K half

#define STAGE_KV(t, jb)                                              \
  {                                                                  \
    const u16* ks_ = kh + (size_t)(t) * 4096;                        \
    const u16* vs_ = vh + (t) * 64;                                  \
    u16* lb_ = lds + (jb) * 8192;                                    \
    GLL16(ks_ + koff0, lb_ + dk0);                                   \
    GLL16(ks_ + koff1, lb_ + dk1);                                   \
    GLL16(vs_ + voff0, lb_ + 4096 + dk0);                            \
    GLL16(vs_ + voff1, lb_ + 4096 + dk1);                            \
  }

  STAGE_KV(0, 0);
  STAGE_KV(1, 1);

  // Q B-fragments in registers (issued after GLLs so vmcnt(4) math holds)
  bf16x8 qr[2][2];
#pragma unroll
  for (int qi = 0; qi < 2; qi++)
#pragma unroll
    for (int ks = 0; ks < 2; ks++)
      qr[qi][ks] = *(const bf16x8*)(
          qh + (size_t)(n0 + wq * 32 + qi * 16 + lr) * 64 + ks * 32 + lg * 8);
  asm volatile("" ::: "memory");   // pin issue order before the loop

  f32x4 z = {0.f, 0.f, 0.f, 0.f};
  f32x4 cacc[4][2];
#pragma unroll
  for (int di = 0; di < 4; di++) { cacc[di][0] = z; cacc[di][1] = z; }

  const int lswz = lr & 7;
  int bi = 0, bs = 2;
  for (int t = 0; t < 32; t++) {
    // my tile-t loads done (tile t+1 stays in flight); then publish.
    if (t < 31) asm volatile("s_waitcnt vmcnt(4)" ::: "memory");
    else        asm volatile("s_waitcnt vmcnt(0)" ::: "memory");
    __builtin_amdgcn_s_barrier();
    asm volatile("" ::: "memory");
    if (t + 2 < 32) { STAGE_KV(t + 2, bs); bs = (bs == 2) ? 0 : bs + 1; }

    const u16* lk = lds + bi * 8192;
    const u16* lv = lds + bi * 8192 + 4096;
#pragma unroll
    for (int ki = 0; ki < 4; ki++) {
      f32x4 s0 = z, s1 = z;
#pragma unroll
      for (int ks = 0; ks < 2; ks++) {
        bf16x8 kf = *(const bf16x8*)(
            lk + (ki * 16 + lr) * 64 + (((ks * 4 + lg) ^ lswz) * 8));
        s0 = MFMA16(kf, qr[0][ks], s0);
        s1 = MFMA16(kf, qr[1][ks], s1);
      }
      bf16x4 p0, p1;
#pragma unroll
      for (int r = 0; r < 4; r++) {
        p0[r] = (__bf16)lrelu(s0[r]);
        p1[r] = (__bf16)lrelu(s1[r]);
      }
#pragma unroll
      for (int di = 0; di < 4; di++) {
        bf16x4 vf = *(const bf16x4*)(
            lv + (di * 16 + lr) * 64 +
            (((ki * 2 + (lg >> 1)) ^ lswz) * 8) + (lg & 1) * 4);
        mfma16x16(cacc[di][0], vf, p0);
        mfma16x16(cacc[di][1], vf, p1);
      }
    }
    bi = (bi == 2) ? 0 : bi + 1;
  }

  // write ctx merged [B,N,H*HD]: lane holds q-col lr, d rows di*16+lg*4+{0..3}
  const int b = bh >> 4, h = bh & 15;
#pragma unroll
  for (int qi = 0; qi < 2; qi++) {
    int n = n0 + wq * 32 + qi * 16 + lr;
    u16* op = ctx + ((size_t)(b * 2048 + n)) * 1024 + h * 64;
#pragma unroll
    for (int di = 0; di < 4; di++) {
      ushort4 o;
      o.x = f2bf(cacc[di][qi][0]);
      o.y = f2bf(cacc[di][qi][1]);
      o.z = f2bf(cacc[di][qi][2]);
      o.w = f2bf(cacc[di][qi][3]);
      *(ushort4*)(op + di * 16 + lg * 4) = o;
    }
  }
#undef STAGE_KV
}

// ---------------------------------------------------------------------------
extern "C" void kernel_launch(void* const* d_in, const int* in_sizes, int n_in,
                              void* d_out, int out_size, void* d_ws, size_t ws_size,
                              hipStream_t stream) {
  (void)in_sizes; (void)n_in; (void)out_size; (void)ws_size;
  const float* x    = (const float*)d_in[0];
  const float* ln1g = (const float*)d_in[1];
  const float* ln1b = (const float*)d_in[2];
  const float* ln2g = (const float*)d_in[3];
  const float* ln2b = (const float*)d_in[4];
  const float* Wq = (const float*)d_in[5];  const float* bq = (const float*)d_in[6];
  const float* Wk = (const float*)d_in[7];  const float* bk = (const float*)d_in[8];
  const float* Wv = (const float*)d_in[9];  const float* bv = (const float*)d_in[10];
  const float* Wo = (const float*)d_in[11]; const float* bo = (const float*)d_in[12];
  const float* W1 = (const float*)d_in[13]; const float* b1 = (const float*)d_in[14];
  const float* W2 = (const float*)d_in[15]; const float* b2 = (const float*)d_in[16];

  char* ws = (char*)d_ws;
  u16*   WqB  = (u16*)(ws + ((size_t)0 << 20));
  u16*   WkB  = (u16*)(ws + ((size_t)2 << 20));
  u16*   WvB  = (u16*)(ws + ((size_t)4 << 20));
  u16*   WoB  = (u16*)(ws + ((size_t)6 << 20));
  u16*   W1B  = (u16*)(ws + ((size_t)8 << 20));
  u16*   W2B  = (u16*)(ws + ((size_t)16 << 20));
  u16*   xn1  = (u16*)(ws + ((size_t)24 << 20));
  u16*   qb   = (u16*)(ws + ((size_t)32 << 20));
  u16*   kb   = (u16*)(ws + ((size_t)40 << 20));
  u16*   vtb  = (u16*)(ws + ((size_t)48 << 20));
  u16*   ctxb = (u16*)(ws + ((size_t)56 << 20));
  float* x2   = (float*)(ws + ((size_t)64 << 20));
  u16*   xn2  = (u16*)(ws + ((size_t)80 << 20));
  u16*   ff1  = (u16*)(ws + ((size_t)88 << 20));
  u16*   pF2  = (u16*)(ws + ((size_t)24 << 20));  // 4 x 8 MiB bf16 partials

  dim3 blk(256);

  cvt6<<<dim3(6144), blk, 0, stream>>>(Wq, Wk, Wv, Wo, W1, W2,
                                       WqB, WkB, WvB, WoB, W1B, W2B);
  ln_k<<<dim3(4096), blk, 0, stream>>>(x, ln1g, ln1b, xn1);
  gemm_qkv<<<dim3(768), blk, 0, stream>>>(xn1, WqB, WkB, WvB, bq, bk, bv,
                                          qb, kb, vtb);
  attn_k<<<dim3(512), blk, 0, stream>>>(qb, kb, vtb, ctxb);
  // Wo projection + residual -> x2 (f32)
  gemm128<0><<<dim3(256), blk, 0, stream>>>(ctxb, WoB, bo, x2, (u16*)nullptr, x,
                                            1024, 8, 256);
  ln_k<<<dim3(4096), blk, 0, stream>>>(x2, ln2g, ln2b, xn2);
  // FFN1 + leaky -> ff1 (bf16)
  gemm128<1><<<dim3(1024), blk, 0, stream>>>(xn2, W1B, b1, (float*)nullptr, ff1,
                                             (const float*)nullptr, 1024, 32, 1024);
  // FFN2 split-K=4 -> bf16 partials, then reduce + bias + residual -> out
  gemm_ffn2<<<dim3(1024), blk, 0, stream>>>(ff1, W2B, pF2);
  reduce_ffn2<<<dim3(4096), blk, 0, stream>>>(pF2, b2, x2, (float*)d_out);
}

// Round 8
// 333.922 us; speedup vs baseline: 1.0595x; 1.0595x over previous
//
#include <hip/hip_runtime.h>
#include <hip/hip_bf16.h>

// ---------------------------------------------------------------------------
// TransformerBlock: LN1 -> QKV -> leaky-relu attention -> Wo+res -> LN2 ->
//                   FFN1(leaky) -> FFN2+res
// B=2 N=2048 EMB=1024 H=16 HD=64 FFN=4096.
// Round 8: GEMM core rebuilt: BK=64, row stride 128B, XOR-swizzle
// (granule ^= row&7) via pre-swizzled global source + swizzled ds_read
// (rule T21; kills the 8-way bank conflict that pinned MfmaUtil at 22%).
// Ring-2 LDS (64 KB, 2 blocks/CU), counted vmcnt(8), 2 raw barriers/step.
// Attention unchanged (HW-validated P-in-registers, ring-3).
// ---------------------------------------------------------------------------

typedef unsigned short u16;
typedef unsigned int u32;
typedef __bf16 bf16x8 __attribute__((ext_vector_type(8)));
typedef __bf16 bf16x4 __attribute__((ext_vector_type(4)));
typedef float f32x4 __attribute__((ext_vector_type(4)));
typedef unsigned short u16x8 __attribute__((ext_vector_type(8)));
typedef unsigned int u32x2 __attribute__((ext_vector_type(2)));
typedef short s16x4 __attribute__((ext_vector_type(4)));

typedef const __attribute__((address_space(1))) void* as1cv;
typedef __attribute__((address_space(3))) void* as3v;

#define MFMA16(a, b, c) __builtin_amdgcn_mfma_f32_16x16x32_bf16((a), (b), (c), 0, 0, 0)
#define GLL16(g, l) __builtin_amdgcn_global_load_lds((as1cv)(g), (as3v)(l), 16, 0, 0)

__device__ __forceinline__ u16 f2bf(float f) {
  unsigned u = __builtin_bit_cast(unsigned, f);
  u += 0x7fffu + ((u >> 16) & 1u);   // RNE
  return (u16)(u >> 16);
}
__device__ __forceinline__ float bf2f(u16 u) {
  return __builtin_bit_cast(float, ((unsigned)u) << 16);
}
__device__ __forceinline__ float lrelu(float v) { return fmaxf(v, 0.01f * v); }

// PV matrix op: D[16d x 16q] += A[16d x 16k] * B[16k x 16q], bf16 inputs.
__device__ __forceinline__ void mfma16x16(f32x4& c, bf16x4 a, bf16x4 b) {
#if __has_builtin(__builtin_amdgcn_mfma_f32_16x16x16bf16_1k)
  c = __builtin_amdgcn_mfma_f32_16x16x16bf16_1k(
      __builtin_bit_cast(s16x4, a), __builtin_bit_cast(s16x4, b), c, 0, 0, 0);
#else
  u32x2 au = __builtin_bit_cast(u32x2, a);
  u32x2 bu = __builtin_bit_cast(u32x2, b);
  asm volatile("s_nop 2\n\tv_mfma_f32_16x16x16_bf16 %0, %1, %2, %0"
               : "+v"(c) : "v"(au), "v"(bu));
#endif
}

// XCD-aware bijective swizzle (nwg % 8 == 0): XCD x gets contiguous chunk.
__device__ __forceinline__ int xcds(int bid, int nwg) {
  int cpx = nwg >> 3;
  return (bid & 7) * cpx + (bid >> 3);
}

// ------------------- weight f32 -> bf16 ------------------------------------
__global__ __launch_bounds__(256) void cvt6(
    const float* __restrict__ p0, const float* __restrict__ p1,
    const float* __restrict__ p2, const float* __restrict__ p3,
    const float* __restrict__ p4, const float* __restrict__ p5,
    u16* __restrict__ o0, u16* __restrict__ o1, u16* __restrict__ o2,
    u16* __restrict__ o3, u16* __restrict__ o4, u16* __restrict__ o5)
{
  int i = blockIdx.x * 256 + threadIdx.x;   // unit = 8 elements
  const float* src; u16* dst; int off;
  if (i < 4 * 131072) {
    int s = i >> 17; off = i & 131071;
    src = (s == 0) ? p0 : (s == 1) ? p1 : (s == 2) ? p2 : p3;
    dst = (s == 0) ? o0 : (s == 1) ? o1 : (s == 2) ? o2 : o3;
  } else {
    int j = i - 4 * 131072;
    int s = j >> 19; off = j & 524287;
    src = s ? p5 : p4;
    dst = s ? o5 : o4;
  }
  const float4* s4 = (const float4*)src;
  float4 a = s4[(size_t)off * 2], b = s4[(size_t)off * 2 + 1];
  u16x8 o = { f2bf(a.x), f2bf(a.y), f2bf(a.z), f2bf(a.w),
              f2bf(b.x), f2bf(b.y), f2bf(b.z), f2bf(b.w) };
  *(u16x8*)(dst + (size_t)off * 8) = o;
}

// ------------------- LayerNorm row (1024) f32 -> bf16 ----------------------
__global__ __launch_bounds__(256) void ln_k(
    const float* __restrict__ x, const float* __restrict__ g,
    const float* __restrict__ bb, u16* __restrict__ out)
{
  const int tid = threadIdx.x;
  const int row = blockIdx.x;
  const float4* xr = (const float4*)(x + (size_t)row * 1024);
  float4 v = xr[tid];
  float s  = v.x + v.y + v.z + v.w;
  float s2 = v.x*v.x + v.y*v.y + v.z*v.z + v.w*v.w;
#pragma unroll
  for (int o = 32; o > 0; o >>= 1) { s += __shfl_down(s, o, 64); s2 += __shfl_down(s2, o, 64); }
  __shared__ float sh[8];
  if ((tid & 63) == 0) { sh[tid >> 6] = s; sh[4 + (tid >> 6)] = s2; }
  __syncthreads();
  s  = sh[0] + sh[1] + sh[2] + sh[3];
  s2 = sh[4] + sh[5] + sh[6] + sh[7];
  float mu  = s * (1.0f / 1024.0f);
  float var = s2 * (1.0f / 1024.0f) - mu * mu;
  float rs  = rsqrtf(var + 1e-6f);
  float4 gv = ((const float4*)g)[tid];
  float4 bv = ((const float4*)bb)[tid];
  ushort4 o;
  o.x = f2bf((v.x - mu) * rs * gv.x + bv.x);
  o.y = f2bf((v.y - mu) * rs * gv.y + bv.y);
  o.z = f2bf((v.z - mu) * rs * gv.z + bv.z);
  o.w = f2bf((v.w - mu) * rs * gv.w + bv.w);
  ((ushort4*)out)[(size_t)row * 256 + tid] = o;
}

// ------------------- GEMM core v3: C[128,128], A[M,K] x W[N,K]^T -----------
// 256 threads = 4 waves (2x2 of 64x64). BK=64 (row stride 128B).
// LDS [128 rows][8 granules of 16B]; stored granule g holds global granule
// g ^ (row&7) (pre-swizzled SOURCE, linear GLL dest); reads apply the same
// XOR -> 2-way bank aliasing (free). Ring-2 (A+B = 64 KB, 2 blocks/CU):
//   loop t: vmcnt(8) [drain tile t, keep t+1] ; bar ; compute buf t&1 ;
//           bar ; stage tile t+2 into buf t&1.
__device__ __forceinline__ void gemm_core128(
    const u16* __restrict__ A, const u16* __restrict__ W,
    int kstride, int klen,
    int row0, int wrow0, u16* lsA, u16* lsB, f32x4 (&acc)[4][4])
{
  const int tid  = threadIdx.x;
  const int lane = tid & 63, wave = tid >> 6;
  const int wr = wave >> 1, wc = wave & 1;
  const int lr = lane & 15, lg = lane >> 4;

  // staging map: GLL instr j covers LDS rows [j*32, j*32+32); thread tid ->
  // (row = j*32 + tid/8, stored granule = tid%8). Source granule = stored ^ (row&7).
  const int srow = tid >> 3;                    // 0..31
  const int sg   = (tid & 7) ^ (srow & 7);      // pre-swizzled source granule
  const u16* ga0 = A + (size_t)(row0 +  0 + srow) * kstride + sg * 8;
  const u16* ga1 = A + (size_t)(row0 + 32 + srow) * kstride + sg * 8;
  const u16* ga2 = A + (size_t)(row0 + 64 + srow) * kstride + sg * 8;
  const u16* ga3 = A + (size_t)(row0 + 96 + srow) * kstride + sg * 8;
  const u16* gb0 = W + (size_t)(wrow0 +  0 + srow) * kstride + sg * 8;
  const u16* gb1 = W + (size_t)(wrow0 + 32 + srow) * kstride + sg * 8;
  const u16* gb2 = W + (size_t)(wrow0 + 64 + srow) * kstride + sg * 8;
  const u16* gb3 = W + (size_t)(wrow0 + 96 + srow) * kstride + sg * 8;
  u16* la = lsA + tid * 8;        // linear dest (GLL rule): wave base + lane*16B
  u16* lb = lsB + tid * 8;

#define GSTAGE(buf)                                                   \
  {                                                                   \
    GLL16(ga0, la + (buf) * 8192 + 0 * 2048);                         \
    GLL16(ga1, la + (buf) * 8192 + 1 * 2048);                         \
    GLL16(ga2, la + (buf) * 8192 + 2 * 2048);                         \
    GLL16(ga3, la + (buf) * 8192 + 3 * 2048);                         \
    GLL16(gb0, lb + (buf) * 8192 + 0 * 2048);                         \
    GLL16(gb1, lb + (buf) * 8192 + 1 * 2048);                         \
    GLL16(gb2, lb + (buf) * 8192 + 2 * 2048);                         \
    GLL16(gb3, lb + (buf) * 8192 + 3 * 2048);                         \
    ga0 += 64; ga1 += 64; ga2 += 64; ga3 += 64;                       \
    gb0 += 64; gb1 += 64; gb2 += 64; gb3 += 64;                       \
  }

  const int nsteps = klen >> 6;
  GSTAGE(0); GSTAGE(1);               // prologue: tiles 0,1 in flight

  const int swzr = lr & 7;            // (row & 7) for all rows this lane reads
  for (int t = 0; t < nsteps; t++) {
    if (t + 1 < nsteps) asm volatile("s_waitcnt vmcnt(8)" ::: "memory");
    else                asm volatile("s_waitcnt vmcnt(0)" ::: "memory");
    __builtin_amdgcn_s_barrier();
    asm volatile("" ::: "memory");

    const u16* cA = lsA + (t & 1) * 8192;
    const u16* cB = lsB + (t & 1) * 8192;
#pragma unroll
    for (int ks = 0; ks < 2; ks++) {
      bf16x8 av[4], bv[4];
#pragma unroll
      for (int mi = 0; mi < 4; mi++)
        av[mi] = *reinterpret_cast<const bf16x8*>(
            cA + (wr * 64 + mi * 16 + lr) * 64 + (((ks * 4 + lg) ^ swzr) * 8));
#pragma unroll
      for (int ni = 0; ni < 4; ni++)
        bv[ni] = *reinterpret_cast<const bf16x8*>(
            cB + (wc * 64 + ni * 16 + lr) * 64 + (((ks * 4 + lg) ^ swzr) * 8));
#pragma unroll
      for (int mi = 0; mi < 4; mi++)
#pragma unroll
        for (int ni = 0; ni < 4; ni++)
          acc[mi][ni] = MFMA16(av[mi], bv[ni], acc[mi][ni]);
    }

    __builtin_amdgcn_s_barrier();     // all waves done reading buf t&1
    asm volatile("" ::: "memory");
    if (t + 2 < nsteps) GSTAGE(t & 1);
  }
#undef GSTAGE
}

// ------------------- fused QKV GEMM: N=3072, scatter epilogue --------------
// q stored pre-scaled by 1/8 (folds the 1/sqrt(HD) of the attention scores).
__global__ __launch_bounds__(256, 2) void gemm_qkv(
    const u16* __restrict__ xn,
    const u16* __restrict__ Wq, const u16* __restrict__ Wk, const u16* __restrict__ Wv,
    const float* __restrict__ bq, const float* __restrict__ bk, const float* __restrict__ bv,
    u16* __restrict__ qb, u16* __restrict__ kb, u16* __restrict__ vtb)
{
  __shared__ u16 lsA[2 * 8192];   // 32 KB
  __shared__ u16 lsB[2 * 8192];   // 32 KB
  const int wid = xcds(blockIdx.x, 768);
  const int mt = wid / 24, nt = wid % 24;
  const int row0 = mt * 128, col0 = nt * 128;
  const int sel = col0 >> 10, c0 = col0 & 1023;
  const u16* W = (sel == 0) ? Wq : (sel == 1) ? Wk : Wv;
  const float* bias = (sel == 0) ? bq : (sel == 1) ? bk : bv;

  f32x4 acc[4][4];
  f32x4 z = {0.f, 0.f, 0.f, 0.f};
#pragma unroll
  for (int mi = 0; mi < 4; mi++)
#pragma unroll
    for (int ni = 0; ni < 4; ni++) acc[mi][ni] = z;

  gemm_core128(xn, W, 1024, 1024, row0, c0, lsA, lsB, acc);

  const int lane = threadIdx.x & 63, wave = threadIdx.x >> 6;
  const int wr = wave >> 1, wc = wave & 1;
  const int lr = lane & 15, lg = lane >> 4;
  const float qscale = (sel == 0) ? 0.125f : 1.0f;
#pragma unroll
  for (int ni = 0; ni < 4; ni++) {
    int c = c0 + wc * 64 + ni * 16 + lr;        // 0..1023 within selected proj
    float bsv = bias[c];
    int h = c >> 6, hd = c & 63;
#pragma unroll
    for (int mi = 0; mi < 4; mi++) {
      int rbase = row0 + wr * 64 + mi * 16 + lg * 4;   // global row (4-aligned)
      int b = rbase >> 11;
      int n = rbase & 2047;
      if (sel < 2) {                 // q,k -> [B,H,N,HD]
        u16* dst = (sel == 0) ? qb : kb;
        size_t base = ((size_t)(b * 16 + h) * 2048 + n) * 64 + hd;
#pragma unroll
        for (int r = 0; r < 4; r++)
          dst[base + (size_t)r * 64] = f2bf((acc[mi][ni][r] + bsv) * qscale);
      } else {                       // v -> transposed [B,H,HD,N]
        size_t base = ((size_t)((b * 16 + h) * 64 + hd)) * 2048 + n;
        ushort4 o;
        o.x = f2bf(acc[mi][ni][0] + bsv);
        o.y = f2bf(acc[mi][ni][1] + bsv);
        o.z = f2bf(acc[mi][ni][2] + bsv);
        o.w = f2bf(acc[mi][ni][3] + bsv);
        *(ushort4*)(vtb + base) = o;
      }
    }
  }
}

// ------------------- generic GEMM + epilogue -------------------------------
// EPI 0: outf[idx] = acc + bias + extra[idx]           (f32; Wo+res)
// EPI 1: outh[idx] = bf16(lrelu(acc + bias))           (FFN1)
template <int EPI>
__global__ __launch_bounds__(256, 2) void gemm128(
    const u16* __restrict__ A, const u16* __restrict__ W,
    const float* __restrict__ bias, float* __restrict__ outf,
    u16* __restrict__ outh, const float* __restrict__ extra,
    int K, int nTiles, int nwg)
{
  __shared__ u16 lsA[2 * 8192];
  __shared__ u16 lsB[2 * 8192];
  const int wid = xcds(blockIdx.x, nwg);
  const int mt = wid / nTiles, nt = wid % nTiles;
  const int row0 = mt * 128, col0 = nt * 128;

  f32x4 acc[4][4];
  f32x4 z = {0.f, 0.f, 0.f, 0.f};
#pragma unroll
  for (int mi = 0; mi < 4; mi++)
#pragma unroll
    for (int ni = 0; ni < 4; ni++) acc[mi][ni] = z;

  gemm_core128(A, W, K, K, row0, col0, lsA, lsB, acc);

  const int N = nTiles * 128;
  const int lane = threadIdx.x & 63, wave = threadIdx.x >> 6;
  const int wr = wave >> 1, wc = wave & 1;
  const int lr = lane & 15, lg = lane >> 4;
#pragma unroll
  for (int ni = 0; ni < 4; ni++) {
    int col = col0 + wc * 64 + ni * 16 + lr;
    float bsv = bias[col];
#pragma unroll
    for (int mi = 0; mi < 4; mi++) {
      int rbase = row0 + wr * 64 + mi * 16 + lg * 4;
#pragma unroll
      for (int r = 0; r < 4; r++) {
        float v = acc[mi][ni][r] + bsv;
        size_t idx = (size_t)(rbase + r) * N + col;
        if (EPI == 0) {
          outf[idx] = v + extra[idx];
        } else {
          outh[idx] = f2bf(lrelu(v));
        }
      }
    }
  }
}

// ------------------- FFN2 split-K GEMM: 4 chunks of K=1024 -----------------
__global__ __launch_bounds__(256, 2) void gemm_ffn2(
    const u16* __restrict__ A, const u16* __restrict__ W,
    u16* __restrict__ pout)
{
  __shared__ u16 lsA[2 * 8192];
  __shared__ u16 lsB[2 * 8192];
  const int wid = xcds(blockIdx.x, 1024);
  const int chunk = wid >> 8, rem = wid & 255;
  const int mt = rem >> 3, nt = rem & 7;
  const int row0 = mt * 128, col0 = nt * 128;

  f32x4 acc[4][4];
  f32x4 z = {0.f, 0.f, 0.f, 0.f};
#pragma unroll
  for (int mi = 0; mi < 4; mi++)
#pragma unroll
    for (int ni = 0; ni < 4; ni++) acc[mi][ni] = z;

  gemm_core128(A + chunk * 1024, W + chunk * 1024, 4096, 1024,
               row0, col0, lsA, lsB, acc);

  u16* out = pout + (size_t)chunk * (4096 * 1024);
  const int lane = threadIdx.x & 63, wave = threadIdx.x >> 6;
  const int wr = wave >> 1, wc = wave & 1;
  const int lr = lane & 15, lg = lane >> 4;
#pragma unroll
  for (int ni = 0; ni < 4; ni++) {
    int col = col0 + wc * 64 + ni * 16 + lr;
#pragma unroll
    for (int mi = 0; mi < 4; mi++) {
      int rbase = row0 + wr * 64 + mi * 16 + lg * 4;
#pragma unroll
      for (int r = 0; r < 4; r++)
        out[(size_t)(rbase + r) * 1024 + col] = f2bf(acc[mi][ni][r]);
    }
  }
}

// ------------------- FFN2 reduce: out = sum(4 partials) + b2 + x2 ----------
__global__ __launch_bounds__(256) void reduce_ffn2(
    const u16* __restrict__ p, const float* __restrict__ b2,
    const float* __restrict__ x2, float* __restrict__ out)
{
  size_t i = ((size_t)blockIdx.x * 256 + threadIdx.x) * 4;
  int col = (int)(i & 1023);
  ushort4 a0 = *(const ushort4*)(p + i);
  ushort4 a1 = *(const ushort4*)(p + (size_t)(4096 * 1024) + i);
  ushort4 a2 = *(const ushort4*)(p + (size_t)(2 * 4096 * 1024) + i);
  ushort4 a3 = *(const ushort4*)(p + (size_t)(3 * 4096 * 1024) + i);
  float4 bv = *(const float4*)(b2 + col);
  float4 xv = *(const float4*)(x2 + i);
  float4 r;
  r.x = bf2f(a0.x) + bf2f(a1.x) + bf2f(a2.x) + bf2f(a3.x) + bv.x + xv.x;
  r.y = bf2f(a0.y) + bf2f(a1.y) + bf2f(a2.y) + bf2f(a3.y) + bv.y + xv.y;
  r.z = bf2f(a0.z) + bf2f(a1.z) + bf2f(a2.z) + bf2f(a3.z) + bv.z + xv.z;
  r.w = bf2f(a0.w) + bf2f(a1.w) + bf2f(a2.w) + bf2f(a3.w) + bv.w + xv.w;
  *(float4*)(out + i) = r;
}

// ------------------- attention v2: P in registers, ring-3 ------------------
// (unchanged from round 7 — HW-validated)
__global__ __launch_bounds__(256, 3) void attn_k(
    const u16* __restrict__ qb, const u16* __restrict__ kb,
    const u16* __restrict__ vtb, u16* __restrict__ ctx)
{
  __shared__ u16 lds[3 * 8192];   // 3 bufs x (K[64][64] + Vt[64][64]) = 48 KB

  const int tid = threadIdx.x;
  const int lane = tid & 63, wq = tid >> 6;
  const int lr = lane & 15, lg = lane >> 4;
  const int wid = xcds(blockIdx.x, 512);
  const int bh = wid >> 4, qt = wid & 15;
  const int n0 = qt * 128;
  const u16* qh = qb + (size_t)bh * 2048 * 64;
  const u16* kh = kb + (size_t)bh * 2048 * 64;
  const u16* vh = vtb + (size_t)bh * 64 * 2048;

  const int srow = tid >> 3;
  const int sgg  = (tid & 7) ^ (srow & 7);
  const size_t koff0 = (size_t)srow * 64 + sgg * 8;
  const size_t koff1 = koff0 + (size_t)32 * 64;
  const size_t voff0 = (size_t)srow * 2048 + sgg * 8;
  const size_t voff1 = voff0 + (size_t)32 * 2048;
  const int dk0 = tid * 8, dk1 = tid * 8 + 2048;  // u16 units inside K half

#define STAGE_KV(t, jb)                                              \
  {                                                                  \
    const u16* ks_ = kh + (size_t)(t) * 4096;                        \
    const u16* vs_ = vh + (t) * 64;                                  \
    u16* lb_ = lds + (jb) * 8192;                                    \
    GLL16(ks_ + koff0, lb_ + dk0);                                   \
    GLL16(ks_ + koff1, lb_ + dk1);                                   \
    GLL16(vs_ + voff0, lb_ + 4096 + dk0);                            \
    GLL16(vs_ + voff1, lb_ + 4096 + dk1);                            \
  }

  STAGE_KV(0, 0);
  STAGE_KV(1, 1);

  bf16x8 qr[2][2];
#pragma unroll
  for (int qi = 0; qi < 2; qi++)
#pragma unroll
    for (int ks = 0; ks < 2; ks++)
      qr[qi][ks] = *(const bf16x8*)(
          qh + (size_t)(n0 + wq * 32 + qi * 16 + lr) * 64 + ks * 32 + lg * 8);
  asm volatile("" ::: "memory");   // pin issue order before the loop

  f32x4 z = {0.f, 0.f, 0.f, 0.f};
  f32x4 cacc[4][2];
#pragma unroll
  for (int di = 0; di < 4; di++) { cacc[di][0] = z; cacc[di][1] = z; }

  const int lswz = lr & 7;
  int bi = 0, bs = 2;
  for (int t = 0; t < 32; t++) {
    if (t < 31) asm volatile("s_waitcnt vmcnt(4)" ::: "memory");
    else        asm volatile("s_waitcnt vmcnt(0)" ::: "memory");
    __builtin_amdgcn_s_barrier();
    asm volatile("" ::: "memory");
    if (t + 2 < 32) { STAGE_KV(t + 2, bs); bs = (bs == 2) ? 0 : bs + 1; }

    const u16* lk = lds + bi * 8192;
    const u16* lv = lds + bi * 8192 + 4096;
#pragma unroll
    for (int ki = 0; ki < 4; ki++) {
      f32x4 s0 = z, s1 = z;
#pragma unroll
      for (int ks = 0; ks < 2; ks++) {
        bf16x8 kf = *(const bf16x8*)(
            lk + (ki * 16 + lr) * 64 + (((ks * 4 + lg) ^ lswz) * 8));
        s0 = MFMA16(kf, qr[0][ks], s0);
        s1 = MFMA16(kf, qr[1][ks], s1);
      }
      bf16x4 p0, p1;
#pragma unroll
      for (int r = 0; r < 4; r++) {
        p0[r] = (__bf16)lrelu(s0[r]);
        p1[r] = (__bf16)lrelu(s1[r]);
      }
#pragma unroll
      for (int di = 0; di < 4; di++) {
        bf16x4 vf = *(const bf16x4*)(
            lv + (di * 16 + lr) * 64 +
            (((ki * 2 + (lg >> 1)) ^ lswz) * 8) + (lg & 1) * 4);
        mfma16x16(cacc[di][0], vf, p0);
        mfma16x16(cacc[di][1], vf, p1);
      }
    }
    bi = (bi == 2) ? 0 : bi + 1;
  }

  const int b = bh >> 4, h = bh & 15;
#pragma unroll
  for (int qi = 0; qi < 2; qi++) {
    int n = n0 + wq * 32 + qi * 16 + lr;
    u16* op = ctx + ((size_t)(b * 2048 + n)) * 1024 + h * 64;
#pragma unroll
    for (int di = 0; di < 4; di++) {
      ushort4 o;
      o.x = f2bf(cacc[di][qi][0]);
      o.y = f2bf(cacc[di][qi][1]);
      o.z = f2bf(cacc[di][qi][2]);
      o.w = f2bf(cacc[di][qi][3]);
      *(ushort4*)(op + di * 16 + lg * 4) = o;
    }
  }
#undef STAGE_KV
}

// ---------------------------------------------------------------------------
extern "C" void kernel_launch(void* const* d_in, const int* in_sizes, int n_in,
                              void* d_out, int out_size, void* d_ws, size_t ws_size,
                              hipStream_t stream) {
  (void)in_sizes; (void)n_in; (void)out_size; (void)ws_size;
  const float* x    = (const float*)d_in[0];
  const float* ln1g = (const float*)d_in[1];
  const float* ln1b = (const float*)d_in[2];
  const float* ln2g = (const float*)d_in[3];
  const float* ln2b = (const float*)d_in[4];
  const float* Wq = (const float*)d_in[5];  const float* bq = (const float*)d_in[6];
  const float* Wk = (const float*)d_in[7];  const float* bk = (const float*)d_in[8];
  const float* Wv = (const float*)d_in[9];  const float* bv = (const float*)d_in[10];
  const float* Wo = (const float*)d_in[11]; const float* bo = (const float*)d_in[12];
  const float* W1 = (const float*)d_in[13]; const float* b1 = (const float*)d_in[14];
  const float* W2 = (const float*)d_in[15]; const float* b2 = (const float*)d_in[16];

  char* ws = (char*)d_ws;
  u16*   WqB  = (u16*)(ws + ((size_t)0 << 20));
  u16*   WkB  = (u16*)(ws + ((size_t)2 << 20));
  u16*   WvB  = (u16*)(ws + ((size_t)4 << 20));
  u16*   WoB  = (u16*)(ws + ((size_t)6 << 20));
  u16*   W1B  = (u16*)(ws + ((size_t)8 << 20));
  u16*   W2B  = (u16*)(ws + ((size_t)16 << 20));
  u16*   xn1  = (u16*)(ws + ((size_t)24 << 20));
  u16*   qb   = (u16*)(ws + ((size_t)32 << 20));
  u16*   kb   = (u16*)(ws + ((size_t)40 << 20));
  u16*   vtb  = (u16*)(ws + ((size_t)48 << 20));
  u16*   ctxb = (u16*)(ws + ((size_t)56 << 20));
  float* x2   = (float*)(ws + ((size_t)64 << 20));
  u16*   xn2  = (u16*)(ws + ((size_t)80 << 20));
  u16*   ff1  = (u16*)(ws + ((size_t)88 << 20));
  u16*   pF2  = (u16*)(ws + ((size_t)24 << 20));  // 4 x 8 MiB bf16 partials

  dim3 blk(256);

  cvt6<<<dim3(6144), blk, 0, stream>>>(Wq, Wk, Wv, Wo, W1, W2,
                                       WqB, WkB, WvB, WoB, W1B, W2B);
  ln_k<<<dim3(4096), blk, 0, stream>>>(x, ln1g, ln1b, xn1);
  gemm_qkv<<<dim3(768), blk, 0, stream>>>(xn1, WqB, WkB, WvB, bq, bk, bv,
                                          qb, kb, vtb);
  attn_k<<<dim3(512), blk, 0, stream>>>(qb, kb, vtb, ctxb);
  // Wo projection + residual -> x2 (f32)
  gemm128<0><<<dim3(256), blk, 0, stream>>>(ctxb, WoB, bo, x2, (u16*)nullptr, x,
                                            1024, 8, 256);
  ln_k<<<dim3(4096), blk, 0, stream>>>(x2, ln2g, ln2b, xn2);
  // FFN1 + leaky -> ff1 (bf16)
  gemm128<1><<<dim3(1024), blk, 0, stream>>>(xn2, W1B, b1, (float*)nullptr, ff1,
                                             (const float*)nullptr, 1024, 32, 1024);
  // FFN2 split-K=4 -> bf16 partials, then reduce + bias + residual -> out
  gemm_ffn2<<<dim3(1024), blk, 0, stream>>>(ff1, W2B, pF2);
  reduce_ffn2<<<dim3(4096), blk, 0, stream>>>(pF2, b2, x2, (float*)d_out);
}

// Round 9
// 333.590 us; speedup vs baseline: 1.0606x; 1.0010x over previous
//
#include <hip/hip_runtime.h>
#include <hip/hip_bf16.h>

// ---------------------------------------------------------------------------
// TransformerBlock: LN1 -> QKV -> leaky-relu attention -> Wo+res -> LN2 ->
//                   FFN1(leaky) -> FFN2+res
// B=2 N=2048 EMB=1024 H=16 HD=64 FFN=4096.
// Round 9: FFN1/FFN2 move to a 256x256 8-wave core (wave tile 128x64,
// bytes/FLOP 0.023 -> MFMA-bound; the 128x128 4-wave core's 64x64 wave tile
// is LDS-BW-bound at ~81%). BK=64, ring-2, 128 KiB LDS, 1 block/CU,
// counted vmcnt(8), pre-swizzled-source XOR (validated round 8).
// QKV/Wo stay on the 128x128 core; attention unchanged (controls).
// ---------------------------------------------------------------------------

typedef unsigned short u16;
typedef unsigned int u32;
typedef __bf16 bf16x8 __attribute__((ext_vector_type(8)));
typedef __bf16 bf16x4 __attribute__((ext_vector_type(4)));
typedef float f32x4 __attribute__((ext_vector_type(4)));
typedef unsigned short u16x8 __attribute__((ext_vector_type(8)));
typedef unsigned int u32x2 __attribute__((ext_vector_type(2)));
typedef short s16x4 __attribute__((ext_vector_type(4)));

typedef const __attribute__((address_space(1))) void* as1cv;
typedef __attribute__((address_space(3))) void* as3v;

#define MFMA16(a, b, c) __builtin_amdgcn_mfma_f32_16x16x32_bf16((a), (b), (c), 0, 0, 0)
#define GLL16(g, l) __builtin_amdgcn_global_load_lds((as1cv)(g), (as3v)(l), 16, 0, 0)

__device__ __forceinline__ u16 f2bf(float f) {
  unsigned u = __builtin_bit_cast(unsigned, f);
  u += 0x7fffu + ((u >> 16) & 1u);   // RNE
  return (u16)(u >> 16);
}
__device__ __forceinline__ float bf2f(u16 u) {
  return __builtin_bit_cast(float, ((unsigned)u) << 16);
}
__device__ __forceinline__ float lrelu(float v) { return fmaxf(v, 0.01f * v); }

// PV matrix op: D[16d x 16q] += A[16d x 16k] * B[16k x 16q], bf16 inputs.
__device__ __forceinline__ void mfma16x16(f32x4& c, bf16x4 a, bf16x4 b) {
#if __has_builtin(__builtin_amdgcn_mfma_f32_16x16x16bf16_1k)
  c = __builtin_amdgcn_mfma_f32_16x16x16bf16_1k(
      __builtin_bit_cast(s16x4, a), __builtin_bit_cast(s16x4, b), c, 0, 0, 0);
#else
  u32x2 au = __builtin_bit_cast(u32x2, a);
  u32x2 bu = __builtin_bit_cast(u32x2, b);
  asm volatile("s_nop 2\n\tv_mfma_f32_16x16x16_bf16 %0, %1, %2, %0"
               : "+v"(c) : "v"(au), "v"(bu));
#endif
}

// XCD-aware bijective swizzle (nwg % 8 == 0): XCD x gets contiguous chunk.
__device__ __forceinline__ int xcds(int bid, int nwg) {
  int cpx = nwg >> 3;
  return (bid & 7) * cpx + (bid >> 3);
}

// ------------------- weight f32 -> bf16 ------------------------------------
__global__ __launch_bounds__(256) void cvt6(
    const float* __restrict__ p0, const float* __restrict__ p1,
    const float* __restrict__ p2, const float* __restrict__ p3,
    const float* __restrict__ p4, const float* __restrict__ p5,
    u16* __restrict__ o0, u16* __restrict__ o1, u16* __restrict__ o2,
    u16* __restrict__ o3, u16* __restrict__ o4, u16* __restrict__ o5)
{
  int i = blockIdx.x * 256 + threadIdx.x;   // unit = 8 elements
  const float* src; u16* dst; int off;
  if (i < 4 * 131072) {
    int s = i >> 17; off = i & 131071;
    src = (s == 0) ? p0 : (s == 1) ? p1 : (s == 2) ? p2 : p3;
    dst = (s == 0) ? o0 : (s == 1) ? o1 : (s == 2) ? o2 : o3;
  } else {
    int j = i - 4 * 131072;
    int s = j >> 19; off = j & 524287;
    src = s ? p5 : p4;
    dst = s ? o5 : o4;
  }
  const float4* s4 = (const float4*)src;
  float4 a = s4[(size_t)off * 2], b = s4[(size_t)off * 2 + 1];
  u16x8 o = { f2bf(a.x), f2bf(a.y), f2bf(a.z), f2bf(a.w),
              f2bf(b.x), f2bf(b.y), f2bf(b.z), f2bf(b.w) };
  *(u16x8*)(dst + (size_t)off * 8) = o;
}

// ------------------- LayerNorm row (1024) f32 -> bf16 ----------------------
__global__ __launch_bounds__(256) void ln_k(
    const float* __restrict__ x, const float* __restrict__ g,
    const float* __restrict__ bb, u16* __restrict__ out)
{
  const int tid = threadIdx.x;
  const int row = blockIdx.x;
  const float4* xr = (const float4*)(x + (size_t)row * 1024);
  float4 v = xr[tid];
  float s  = v.x + v.y + v.z + v.w;
  float s2 = v.x*v.x + v.y*v.y + v.z*v.z + v.w*v.w;
#pragma unroll
  for (int o = 32; o > 0; o >>= 1) { s += __shfl_down(s, o, 64); s2 += __shfl_down(s2, o, 64); }
  __shared__ float sh[8];
  if ((tid & 63) == 0) { sh[tid >> 6] = s; sh[4 + (tid >> 6)] = s2; }
  __syncthreads();
  s  = sh[0] + sh[1] + sh[2] + sh[3];
  s2 = sh[4] + sh[5] + sh[6] + sh[7];
  float mu  = s * (1.0f / 1024.0f);
  float var = s2 * (1.0f / 1024.0f) - mu * mu;
  float rs  = rsqrtf(var + 1e-6f);
  float4 gv = ((const float4*)g)[tid];
  float4 bv = ((const float4*)bb)[tid];
  ushort4 o;
  o.x = f2bf((v.x - mu) * rs * gv.x + bv.x);
  o.y = f2bf((v.y - mu) * rs * gv.y + bv.y);
  o.z = f2bf((v.z - mu) * rs * gv.z + bv.z);
  o.w = f2bf((v.w - mu) * rs * gv.w + bv.w);
  ((ushort4*)out)[(size_t)row * 256 + tid] = o;
}

// ------------------- GEMM core 128: C[128,128], 4 waves (round-8, kept) ----
__device__ __forceinline__ void gemm_core128(
    const u16* __restrict__ A, const u16* __restrict__ W,
    int kstride, int klen,
    int row0, int wrow0, u16* lsA, u16* lsB, f32x4 (&acc)[4][4])
{
  const int tid  = threadIdx.x;
  const int lane = tid & 63, wave = tid >> 6;
  const int wr = wave >> 1, wc = wave & 1;
  const int lr = lane & 15, lg = lane >> 4;

  const int srow = tid >> 3;                    // 0..31
  const int sg   = (tid & 7) ^ (srow & 7);      // pre-swizzled source granule
  const u16* ga0 = A + (size_t)(row0 +  0 + srow) * kstride + sg * 8;
  const u16* ga1 = A + (size_t)(row0 + 32 + srow) * kstride + sg * 8;
  const u16* ga2 = A + (size_t)(row0 + 64 + srow) * kstride + sg * 8;
  const u16* ga3 = A + (size_t)(row0 + 96 + srow) * kstride + sg * 8;
  const u16* gb0 = W + (size_t)(wrow0 +  0 + srow) * kstride + sg * 8;
  const u16* gb1 = W + (size_t)(wrow0 + 32 + srow) * kstride + sg * 8;
  const u16* gb2 = W + (size_t)(wrow0 + 64 + srow) * kstride + sg * 8;
  const u16* gb3 = W + (size_t)(wrow0 + 96 + srow) * kstride + sg * 8;
  u16* la = lsA + tid * 8;
  u16* lb = lsB + tid * 8;

#define GSTAGE(buf)                                                   \
  {                                                                   \
    GLL16(ga0, la + (buf) * 8192 + 0 * 2048);                         \
    GLL16(ga1, la + (buf) * 8192 + 1 * 2048);                         \
    GLL16(ga2, la + (buf) * 8192 + 2 * 2048);                         \
    GLL16(ga3, la + (buf) * 8192 + 3 * 2048);                         \
    GLL16(gb0, lb + (buf) * 8192 + 0 * 2048);                         \
    GLL16(gb1, lb + (buf) * 8192 + 1 * 2048);                         \
    GLL16(gb2, lb + (buf) * 8192 + 2 * 2048);                         \
    GLL16(gb3, lb + (buf) * 8192 + 3 * 2048);                         \
    ga0 += 64; ga1 += 64; ga2 += 64; ga3 += 64;                       \
    gb0 += 64; gb1 += 64; gb2 += 64; gb3 += 64;                       \
  }

  const int nsteps = klen >> 6;
  GSTAGE(0); GSTAGE(1);               // prologue: tiles 0,1 in flight

  const int swzr = lr & 7;
  for (int t = 0; t < nsteps; t++) {
    if (t + 1 < nsteps) asm volatile("s_waitcnt vmcnt(8)" ::: "memory");
    else                asm volatile("s_waitcnt vmcnt(0)" ::: "memory");
    __builtin_amdgcn_s_barrier();
    asm volatile("" ::: "memory");

    const u16* cA = lsA + (t & 1) * 8192;
    const u16* cB = lsB + (t & 1) * 8192;
#pragma unroll
    for (int ks = 0; ks < 2; ks++) {
      bf16x8 av[4], bv[4];
#pragma unroll
      for (int mi = 0; mi < 4; mi++)
        av[mi] = *reinterpret_cast<const bf16x8*>(
            cA + (wr * 64 + mi * 16 + lr) * 64 + (((ks * 4 + lg) ^ swzr) * 8));
#pragma unroll
      for (int ni = 0; ni < 4; ni++)
        bv[ni] = *reinterpret_cast<const bf16x8*>(
            cB + (wc * 64 + ni * 16 + lr) * 64 + (((ks * 4 + lg) ^ swzr) * 8));
#pragma unroll
      for (int mi = 0; mi < 4; mi++)
#pragma unroll
        for (int ni = 0; ni < 4; ni++)
          acc[mi][ni] = MFMA16(av[mi], bv[ni], acc[mi][ni]);
    }

    __builtin_amdgcn_s_barrier();
    asm volatile("" ::: "memory");
    if (t + 2 < nsteps) GSTAGE(t & 1);
  }
#undef GSTAGE
}

// ------------------- GEMM core 256: C[256,256], 8 waves (2Mx4N) ------------
// 512 threads. Wave tile 128x64 -> bytes/FLOP 0.023 -> MFMA-bound.
// BK=64, ring-2, LDS 2 x (256x64) x 2 tensors = 128 KiB, 1 block/CU.
// Same source-swizzle scheme as core128 (stored granule g holds global g^(row&7)).
__device__ __forceinline__ void gemm_core256(
    const u16* __restrict__ A, const u16* __restrict__ W,
    int kstride, int klen,
    int row0, int col0, u16* lsA, u16* lsB, f32x4 (&acc)[8][4])
{
  const int tid  = threadIdx.x;                 // 0..511
  const int lane = tid & 63, wave = tid >> 6;   // 8 waves
  const int wm = wave >> 2, wn = wave & 3;      // 2 x 4
  const int lr = lane & 15, lg = lane >> 4;

  const int srow = tid >> 3;                    // 0..63
  const int sg   = (tid & 7) ^ (srow & 7);
  const u16* ga0 = A + (size_t)(row0 +   0 + srow) * kstride + sg * 8;
  const u16* ga1 = A + (size_t)(row0 +  64 + srow) * kstride + sg * 8;
  const u16* ga2 = A + (size_t)(row0 + 128 + srow) * kstride + sg * 8;
  const u16* ga3 = A + (size_t)(row0 + 192 + srow) * kstride + sg * 8;
  const u16* gb0 = W + (size_t)(col0 +   0 + srow) * kstride + sg * 8;
  const u16* gb1 = W + (size_t)(col0 +  64 + srow) * kstride + sg * 8;
  const u16* gb2 = W + (size_t)(col0 + 128 + srow) * kstride + sg * 8;
  const u16* gb3 = W + (size_t)(col0 + 192 + srow) * kstride + sg * 8;
  u16* la = lsA + tid * 8;          // linear dest: 512 threads x 16B = 8KB/GLL
  u16* lb = lsB + tid * 8;

#define GSTAGE2(buf)                                                  \
  {                                                                   \
    GLL16(ga0, la + (buf) * 16384 + 0 * 4096);                        \
    GLL16(ga1, la + (buf) * 16384 + 1 * 4096);                        \
    GLL16(ga2, la + (buf) * 16384 + 2 * 4096);                        \
    GLL16(ga3, la + (buf) * 16384 + 3 * 4096);                        \
    GLL16(gb0, lb + (buf) * 16384 + 0 * 4096);                        \
    GLL16(gb1, lb + (buf) * 16384 + 1 * 4096);                        \
    GLL16(gb2, lb + (buf) * 16384 + 2 * 4096);                        \
    GLL16(gb3, lb + (buf) * 16384 + 3 * 4096);                        \
    ga0 += 64; ga1 += 64; ga2 += 64; ga3 += 64;                       \
    gb0 += 64; gb1 += 64; gb2 += 64; gb3 += 64;                       \
  }

  const int nsteps = klen >> 6;
  GSTAGE2(0); GSTAGE2(1);             // tiles 0,1 in flight (16 loads)

  const int swzr = lr & 7;
  for (int t = 0; t < nsteps; t++) {
    if (t + 1 < nsteps) asm volatile("s_waitcnt vmcnt(8)" ::: "memory");
    else                asm volatile("s_waitcnt vmcnt(0)" ::: "memory");
    __builtin_amdgcn_s_barrier();
    asm volatile("" ::: "memory");

    const u16* cA = lsA + (t & 1) * 16384;
    const u16* cB = lsB + (t & 1) * 16384;
#pragma unroll
    for (int ks = 0; ks < 2; ks++) {
      bf16x8 av[8], bv[4];
#pragma unroll
      for (int mi = 0; mi < 8; mi++)
        av[mi] = *reinterpret_cast<const bf16x8*>(
            cA + (wm * 128 + mi * 16 + lr) * 64 + (((ks * 4 + lg) ^ swzr) * 8));
#pragma unroll
      for (int ni = 0; ni < 4; ni++)
        bv[ni] = *reinterpret_cast<const bf16x8*>(
            cB + (wn * 64 + ni * 16 + lr) * 64 + (((ks * 4 + lg) ^ swzr) * 8));
#pragma unroll
      for (int mi = 0; mi < 8; mi++)
#pragma unroll
        for (int ni = 0; ni < 4; ni++)
          acc[mi][ni] = MFMA16(av[mi], bv[ni], acc[mi][ni]);
    }

    __builtin_amdgcn_s_barrier();
    asm volatile("" ::: "memory");
    if (t + 2 < nsteps) GSTAGE2(t & 1);
  }
#undef GSTAGE2
}

// ------------------- 256-tile GEMM kernels ---------------------------------
// EPI 1 (FFN1): out bf16[4096] = lrelu(acc + bias)
// EPI 2 (FFN2 split-K partial): out bf16[1024] = acc   (4 chunks of K=1024)
template <int EPI>
__global__ __launch_bounds__(512, 2) void gemm256(
    const u16* __restrict__ A, const u16* __restrict__ W,
    const float* __restrict__ bias, u16* __restrict__ outh)
{
  __shared__ u16 lsA[2 * 16384];   // 64 KB
  __shared__ u16 lsB[2 * 16384];   // 64 KB
  const int wid = xcds(blockIdx.x, 256);
  int row0, col0, kstride;
  if (EPI == 1) {
    row0 = (wid >> 4) * 256; col0 = (wid & 15) * 256; kstride = 1024;
  } else {
    const int chunk = wid >> 6, rem = wid & 63;
    row0 = (rem >> 2) * 256; col0 = (rem & 3) * 256; kstride = 4096;
    A += chunk * 1024; W += chunk * 1024;
    outh += (size_t)chunk * (4096 * 1024);
  }

  f32x4 acc[8][4];
  f32x4 z = {0.f, 0.f, 0.f, 0.f};
#pragma unroll
  for (int mi = 0; mi < 8; mi++)
#pragma unroll
    for (int ni = 0; ni < 4; ni++) acc[mi][ni] = z;

  gemm_core256(A, W, kstride, 1024, row0, col0, lsA, lsB, acc);

  const int lane = threadIdx.x & 63, wave = threadIdx.x >> 6;
  const int wm = wave >> 2, wn = wave & 3;
  const int lr = lane & 15, lg = lane >> 4;
  const int NOUT = (EPI == 1) ? 4096 : 1024;
#pragma unroll
  for (int ni = 0; ni < 4; ni++) {
    int col = col0 + wn * 64 + ni * 16 + lr;
    float bsv = (EPI == 1) ? bias[col] : 0.f;
#pragma unroll
    for (int mi = 0; mi < 8; mi++) {
      int rbase = row0 + wm * 128 + mi * 16 + lg * 4;
#pragma unroll
      for (int r = 0; r < 4; r++) {
        float v = acc[mi][ni][r] + bsv;
        if (EPI == 1) outh[(size_t)(rbase + r) * NOUT + col] = f2bf(lrelu(v));
        else          outh[(size_t)(rbase + r) * NOUT + col] = f2bf(v);
      }
    }
  }
}

// ------------------- fused QKV GEMM: N=3072, scatter epilogue (128 core) ---
__global__ __launch_bounds__(256, 2) void gemm_qkv(
    const u16* __restrict__ xn,
    const u16* __restrict__ Wq, const u16* __restrict__ Wk, const u16* __restrict__ Wv,
    const float* __restrict__ bq, const float* __restrict__ bk, const float* __restrict__ bv,
    u16* __restrict__ qb, u16* __restrict__ kb, u16* __restrict__ vtb)
{
  __shared__ u16 lsA[2 * 8192];   // 32 KB
  __shared__ u16 lsB[2 * 8192];   // 32 KB
  const int wid = xcds(blockIdx.x, 768);
  const int mt = wid / 24, nt = wid % 24;
  const int row0 = mt * 128, col0 = nt * 128;
  const int sel = col0 >> 10, c0 = col0 & 1023;
  const u16* W = (sel == 0) ? Wq : (sel == 1) ? Wk : Wv;
  const float* bias = (sel == 0) ? bq : (sel == 1) ? bk : bv;

  f32x4 acc[4][4];
  f32x4 z = {0.f, 0.f, 0.f, 0.f};
#pragma unroll
  for (int mi = 0; mi < 4; mi++)
#pragma unroll
    for (int ni = 0; ni < 4; ni++) acc[mi][ni] = z;

  gemm_core128(xn, W, 1024, 1024, row0, c0, lsA, lsB, acc);

  const int lane = threadIdx.x & 63, wave = threadIdx.x >> 6;
  const int wr = wave >> 1, wc = wave & 1;
  const int lr = lane & 15, lg = lane >> 4;
  const float qscale = (sel == 0) ? 0.125f : 1.0f;
#pragma unroll
  for (int ni = 0; ni < 4; ni++) {
    int c = c0 + wc * 64 + ni * 16 + lr;        // 0..1023 within selected proj
    float bsv = bias[c];
    int h = c >> 6, hd = c & 63;
#pragma unroll
    for (int mi = 0; mi < 4; mi++) {
      int rbase = row0 + wr * 64 + mi * 16 + lg * 4;   // global row (4-aligned)
      int b = rbase >> 11;
      int n = rbase & 2047;
      if (sel < 2) {                 // q,k -> [B,H,N,HD]
        u16* dst = (sel == 0) ? qb : kb;
        size_t base = ((size_t)(b * 16 + h) * 2048 + n) * 64 + hd;
#pragma unroll
        for (int r = 0; r < 4; r++)
          dst[base + (size_t)r * 64] = f2bf((acc[mi][ni][r] + bsv) * qscale);
      } else {                       // v -> transposed [B,H,HD,N]
        size_t base = ((size_t)((b * 16 + h) * 64 + hd)) * 2048 + n;
        ushort4 o;
        o.x = f2bf(acc[mi][ni][0] + bsv);
        o.y = f2bf(acc[mi][ni][1] + bsv);
        o.z = f2bf(acc[mi][ni][2] + bsv);
        o.w = f2bf(acc[mi][ni][3] + bsv);
        *(ushort4*)(vtb + base) = o;
      }
    }
  }
}

// ------------------- Wo GEMM + bias + residual (128 core) ------------------
__global__ __launch_bounds__(256, 2) void gemm_wo(
    const u16* __restrict__ A, const u16* __restrict__ W,
    const float* __restrict__ bias, float* __restrict__ outf,
    const float* __restrict__ extra)
{
  __shared__ u16 lsA[2 * 8192];
  __shared__ u16 lsB[2 * 8192];
  const int wid = xcds(blockIdx.x, 256);
  const int mt = wid >> 3, nt = wid & 7;
  const int row0 = mt * 128, col0 = nt * 128;

  f32x4 acc[4][4];
  f32x4 z = {0.f, 0.f, 0.f, 0.f};
#pragma unroll
  for (int mi = 0; mi < 4; mi++)
#pragma unroll
    for (int ni = 0; ni < 4; ni++) acc[mi][ni] = z;

  gemm_core128(A, W, 1024, 1024, row0, col0, lsA, lsB, acc);

  const int lane = threadIdx.x & 63, wave = threadIdx.x >> 6;
  const int wr = wave >> 1, wc = wave & 1;
  const int lr = lane & 15, lg = lane >> 4;
#pragma unroll
  for (int ni = 0; ni < 4; ni++) {
    int col = col0 + wc * 64 + ni * 16 + lr;
    float bsv = bias[col];
#pragma unroll
    for (int mi = 0; mi < 4; mi++) {
      int rbase = row0 + wr * 64 + mi * 16 + lg * 4;
#pragma unroll
      for (int r = 0; r < 4; r++) {
        size_t idx = (size_t)(rbase + r) * 1024 + col;
        outf[idx] = acc[mi][ni][r] + bsv + extra[idx];
      }
    }
  }
}

// ------------------- FFN2 reduce: out = sum(4 partials) + b2 + x2 ----------
__global__ __launch_bounds__(256) void reduce_ffn2(
    const u16* __restrict__ p, const float* __restrict__ b2,
    const float* __restrict__ x2, float* __restrict__ out)
{
  size_t i = ((size_t)blockIdx.x * 256 + threadIdx.x) * 4;
  int col = (int)(i & 1023);
  ushort4 a0 = *(const ushort4*)(p + i);
  ushort4 a1 = *(const ushort4*)(p + (size_t)(4096 * 1024) + i);
  ushort4 a2 = *(const ushort4*)(p + (size_t)(2 * 4096 * 1024) + i);
  ushort4 a3 = *(const ushort4*)(p + (size_t)(3 * 4096 * 1024) + i);
  float4 bv = *(const float4*)(b2 + col);
  float4 xv = *(const float4*)(x2 + i);
  float4 r;
  r.x = bf2f(a0.x) + bf2f(a1.x) + bf2f(a2.x) + bf2f(a3.x) + bv.x + xv.x;
  r.y = bf2f(a0.y) + bf2f(a1.y) + bf2f(a2.y) + bf2f(a3.y) + bv.y + xv.y;
  r.z = bf2f(a0.z) + bf2f(a1.z) + bf2f(a2.z) + bf2f(a3.z) + bv.z + xv.z;
  r.w = bf2f(a0.w) + bf2f(a1.w) + bf2f(a2.w) + bf2f(a3.w) + bv.w + xv.w;
  *(float4*)(out + i) = r;
}

// ------------------- attention v2: P in registers, ring-3 ------------------
// (unchanged — HW-validated)
__global__ __launch_bounds__(256, 3) void attn_k(
    const u16* __restrict__ qb, const u16* __restrict__ kb,
    const u16* __restrict__ vtb, u16* __restrict__ ctx)
{
  __shared__ u16 lds[3 * 8192];   // 3 bufs x (K[64][64] + Vt[64][64]) = 48 KB

  const int tid = threadIdx.x;
  const int lane = tid & 63, wq = tid >> 6;
  const int lr = lane & 15, lg = lane >> 4;
  const int wid = xcds(blockIdx.x, 512);
  const int bh = wid >> 4, qt = wid & 15;
  const int n0 = qt * 128;
  const u16* qh = qb + (size_t)bh * 2048 * 64;
  const u16* kh = kb + (size_t)bh * 2048 * 64;
  const u16* vh = vtb + (size_t)bh * 64 * 2048;

  const int srow = tid >> 3;
  const int sgg  = (tid & 7) ^ (srow & 7);
  const size_t koff0 = (size_t)srow * 64 + sgg * 8;
  const size_t koff1 = koff0 + (size_t)32 * 64;
  const size_t voff0 = (size_t)srow * 2048 + sgg * 8;
  const size_t voff1 = voff0 + (size_t)32 * 2048;
  const int dk0 = tid * 8, dk1 = tid * 8 + 2048;  // u16 units inside K half

#define STAGE_KV(t, jb)                                              \
  {                                                                  \
    const u16* ks_ = kh + (size_t)(t) * 4096;                        \
    const u16* vs_ = vh + (t) * 64;                                  \
    u16* lb_ = lds + (jb) * 8192;                                    \
    GLL16(ks_ + koff0, lb_ + dk0);                                   \
    GLL16(ks_ + koff1, lb_ + dk1);                                   \
    GLL16(vs_ + voff0, lb_ + 4096 + dk0);                            \
    GLL16(vs_ + voff1, lb_ + 4096 + dk1);                            \
  }

  STAGE_KV(0, 0);
  STAGE_KV(1, 1);

  bf16x8 qr[2][2];
#pragma unroll
  for (int qi = 0; qi < 2; qi++)
#pragma unroll
    for (int ks = 0; ks < 2; ks++)
      qr[qi][ks] = *(const bf16x8*)(
          qh + (size_t)(n0 + wq * 32 + qi * 16 + lr) * 64 + ks * 32 + lg * 8);
  asm volatile("" ::: "memory");   // pin issue order before the loop

  f32x4 z = {0.f, 0.f, 0.f, 0.f};
  f32x4 cacc[4][2];
#pragma unroll
  for (int di = 0; di < 4; di++) { cacc[di][0] = z; cacc[di][1] = z; }

  const int lswz = lr & 7;
  int bi = 0, bs = 2;
  for (int t = 0; t < 32; t++) {
    if (t < 31) asm volatile("s_waitcnt vmcnt(4)" ::: "memory");
    else        asm volatile("s_waitcnt vmcnt(0)" ::: "memory");
    __builtin_amdgcn_s_barrier();
    asm volatile("" ::: "memory");
    if (t + 2 < 32) { STAGE_KV(t + 2, bs); bs = (bs == 2) ? 0 : bs + 1; }

    const u16* lk = lds + bi * 8192;
    const u16* lv = lds + bi * 8192 + 4096;
#pragma unroll
    for (int ki = 0; ki < 4; ki++) {
      f32x4 s0 = z, s1 = z;
#pragma unroll
      for (int ks = 0; ks < 2; ks++) {
        bf16x8 kf = *(const bf16x8*)(
            lk + (ki * 16 + lr) * 64 + (((ks * 4 + lg) ^ lswz) * 8));
        s0 = MFMA16(kf, qr[0][ks], s0);
        s1 = MFMA16(kf, qr[1][ks], s1);
      }
      bf16x4 p0, p1;
#pragma unroll
      for (int r = 0; r < 4; r++) {
        p0[r] = (__bf16)lrelu(s0[r]);
        p1[r] = (__bf16)lrelu(s1[r]);
      }
#pragma unroll
      for (int di = 0; di < 4; di++) {
        bf16x4 vf = *(const bf16x4*)(
            lv + (di * 16 + lr) * 64 +
            (((ki * 2 + (lg >> 1)) ^ lswz) * 8) + (lg & 1) * 4);
        mfma16x16(cacc[di][0], vf, p0);
        mfma16x16(cacc[di][1], vf, p1);
      }
    }
    bi = (bi == 2) ? 0 : bi + 1;
  }

  const int b = bh >> 4, h = bh & 15;
#pragma unroll
  for (int qi = 0; qi < 2; qi++) {
    int n = n0 + wq * 32 + qi * 16 + lr;
    u16* op = ctx + ((size_t)(b * 2048 + n)) * 1024 + h * 64;
#pragma unroll
    for (int di = 0; di < 4; di++) {
      ushort4 o;
      o.x = f2bf(cacc[di][qi][0]);
      o.y = f2bf(cacc[di][qi][1]);
      o.z = f2bf(cacc[di][qi][2]);
      o.w = f2bf(cacc[di][qi][3]);
      *(ushort4*)(op + di * 16 + lg * 4) = o;
    }
  }
#undef STAGE_KV
}

// ---------------------------------------------------------------------------
extern "C" void kernel_launch(void* const* d_in, const int* in_sizes, int n_in,
                              void* d_out, int out_size, void* d_ws, size_t ws_size,
                              hipStream_t stream) {
  (void)in_sizes; (void)n_in; (void)out_size; (void)ws_size;
  const float* x    = (const float*)d_in[0];
  const float* ln1g = (const float*)d_in[1];
  const float* ln1b = (const float*)d_in[2];
  const float* ln2g = (const float*)d_in[3];
  const float* ln2b = (const float*)d_in[4];
  const float* Wq = (const float*)d_in[5];  const float* bq = (const float*)d_in[6];
  const float* Wk = (const float*)d_in[7];  const float* bk = (const float*)d_in[8];
  const float* Wv = (const float*)d_in[9];  const float* bv = (const float*)d_in[10];
  const float* Wo = (const float*)d_in[11]; const float* bo = (const float*)d_in[12];
  const float* W1 = (const float*)d_in[13]; const float* b1 = (const float*)d_in[14];
  const float* W2 = (const float*)d_in[15]; const float* b2 = (const float*)d_in[16];

  char* ws = (char*)d_ws;
  u16*   WqB  = (u16*)(ws + ((size_t)0 << 20));
  u16*   WkB  = (u16*)(ws + ((size_t)2 << 20));
  u16*   WvB  = (u16*)(ws + ((size_t)4 << 20));
  u16*   WoB  = (u16*)(ws + ((size_t)6 << 20));
  u16*   W1B  = (u16*)(ws + ((size_t)8 << 20));
  u16*   W2B  = (u16*)(ws + ((size_t)16 << 20));
  u16*   xn1  = (u16*)(ws + ((size_t)24 << 20));
  u16*   qb   = (u16*)(ws + ((size_t)32 << 20));
  u16*   kb   = (u16*)(ws + ((size_t)40 << 20));
  u16*   vtb  = (u16*)(ws + ((size_t)48 << 20));
  u16*   ctxb = (u16*)(ws + ((size_t)56 << 20));
  float* x2   = (float*)(ws + ((size_t)64 << 20));
  u16*   xn2  = (u16*)(ws + ((size_t)80 << 20));
  u16*   ff1  = (u16*)(ws + ((size_t)88 << 20));
  u16*   pF2  = (u16*)(ws + ((size_t)24 << 20));  // 4 x 8 MiB bf16 partials

  dim3 blk(256);

  cvt6<<<dim3(6144), blk, 0, stream>>>(Wq, Wk, Wv, Wo, W1, W2,
                                       WqB, WkB, WvB, WoB, W1B, W2B);
  ln_k<<<dim3(4096), blk, 0, stream>>>(x, ln1g, ln1b, xn1);
  gemm_qkv<<<dim3(768), blk, 0, stream>>>(xn1, WqB, WkB, WvB, bq, bk, bv,
                                          qb, kb, vtb);
  attn_k<<<dim3(512), blk, 0, stream>>>(qb, kb, vtb, ctxb);
  // Wo projection + residual -> x2 (f32)
  gemm_wo<<<dim3(256), blk, 0, stream>>>(ctxb, WoB, bo, x2, x);
  ln_k<<<dim3(4096), blk, 0, stream>>>(x2, ln2g, ln2b, xn2);
  // FFN1 + leaky -> ff1 (bf16)   [256-tile core, 512 threads]
  gemm256<1><<<dim3(256), dim3(512), 0, stream>>>(xn2, W1B, b1, ff1);
  // FFN2 split-K=4 -> bf16 partials, then reduce + bias + residual -> out
  gemm256<2><<<dim3(256), dim3(512), 0, stream>>>(ff1, W2B, (const float*)nullptr, pF2);
  reduce_ffn2<<<dim3(4096), blk, 0, stream>>>(pF2, b2, x2, (float*)d_out);
}